// Round 12
// baseline (466.075 us; speedup 1.0000x reference)
//
#include <hip/hip_runtime.h>

typedef __bf16 bf16;
typedef __bf16 bf16x4 __attribute__((ext_vector_type(4)));
typedef __bf16 bf16x8 __attribute__((ext_vector_type(8)));
typedef float  f32x4  __attribute__((ext_vector_type(4)));

#define S_LEN 2048
#define D_DIM 1024
#define NHEAD 16
#define DHEAD 64
#define NPAR 4

// ---------------------------------------------------------------------------
// async global->LDS, 16B per lane (wave-uniform LDS base + lane*16, m104).
__device__ __forceinline__ void async_cp16(const bf16* g, bf16* l) {
  __builtin_amdgcn_global_load_lds(
      (__attribute__((address_space(1))) void*)(void*)g,
      (__attribute__((address_space(3))) void*)l,
      16, 0, 0);
}

// ---------------------------------------------------------------------------
// fp32 -> bf16 cvt of x + 4 weights (blocks [0,3072)); block 3072 computes
// per-Q-tile key-block ranges kbr[32][2] from sorted seg_ids AND zeroes the
// 512 split-K arrival counters (ws is re-poisoned 0xAA before every launch).
__global__ __launch_bounds__(256) void cvt_k(
    const float* __restrict__ x,  const float* __restrict__ w0,
    const float* __restrict__ w1, const float* __restrict__ w2,
    const float* __restrict__ w3, bf16* __restrict__ dst,
    const int* __restrict__ seg, int* __restrict__ kbr,
    int* __restrict__ cnt)
{
  __shared__ int firstv[4];
  const int b = blockIdx.x;
  const int t = threadIdx.x;

  if (b < 3072) {
    int i = b * 256 + t;  // 0 .. 786431 (x8 elems)
    const float* src;
    int off;
    if (i < (1 << 18)) {            // x: 2^18 groups of 8
      src = x; off = i;
    } else {
      int j = i - (1 << 18);        // weights: 2^17 groups each
      int s = j >> 17;
      off = j & ((1 << 17) - 1);
      src = (s == 0) ? w0 : (s == 1) ? w1 : (s == 2) ? w2 : w3;
    }
    f32x4 a = *(const f32x4*)(src + (size_t)off * 8);
    f32x4 bb = *(const f32x4*)(src + (size_t)off * 8 + 4);
    bf16x8 o;
    o[0] = (bf16)a[0];  o[1] = (bf16)a[1];  o[2] = (bf16)a[2];  o[3] = (bf16)a[3];
    o[4] = (bf16)bb[0]; o[5] = (bf16)bb[1]; o[6] = (bf16)bb[2]; o[7] = (bf16)bb[3];
    *((bf16x8*)dst + i) = o;
  } else {
    for (int i = t; i < NHEAD * 32; i += 256) cnt[i] = 0;
    if (t < 4) firstv[t] = S_LEN;
    __syncthreads();
    for (int i = t; i < S_LEN; i += 256) {
      int s = seg[i];
      if (i == 0 || seg[i - 1] != s) atomicMin(&firstv[s], i);
    }
    __syncthreads();
    if (t < 32) {
      int smin = seg[t * 64], smax = seg[t * 64 + 63];
      int lb = S_LEN, ub = S_LEN;
      for (int vv = smin; vv < 4; ++vv) lb = min(lb, firstv[vv]);
      for (int vv = smax + 1; vv < 4; ++vv) ub = min(ub, firstv[vv]);
      kbr[t * 2] = lb >> 6;
      kbr[t * 2 + 1] = (ub - 1) >> 6;  // inclusive
    }
  }
}

// ---------------------------------------------------------------------------
// QKV GEMM (R9 — measured best): 128x64 tile, BK=128 via four split 32-k
// LDS arrays (48KB, 3 blocks/CU), DMA staging, 2-barrier K-loop. Epilogue
// by z: z=0 rope*0.125 -> q0; z=1 rope -> k0; z=2 transposed store -> Vt.
__global__ __launch_bounds__(256) void gemm_qkv(
    const bf16* __restrict__ A,
    const bf16* __restrict__ B0, const bf16* __restrict__ B1,
    const bf16* __restrict__ B2,
    const float* __restrict__ cosT, const float* __restrict__ sinT,
    bf16* __restrict__ Cbase, bf16* __restrict__ Vt)
{
  constexpr int K = 1024, N = 1024;
  const int z = blockIdx.z;
  const bf16* W = (z == 0) ? B0 : (z == 1) ? B1 : B2;
  bf16* C = Cbase + (size_t)z * 2048 * 1024;

  __shared__ bf16 As[4][128 * 32] __attribute__((aligned(16)));  // 32KB
  __shared__ bf16 Bs[4][64 * 32] __attribute__((aligned(16)));   // 16KB

  const int t = threadIdx.x;
  const int lane = t & 63;
  const int w = t >> 6;
  const int lm = lane & 15, lq = lane >> 4;
  const int wr = w >> 1, wc = w & 1;
  const int bm = blockIdx.y, bn = blockIdx.x;

  const bf16* Abase = A + (size_t)bm * 128 * K;
  const bf16* Wbase = W + (size_t)bn * 64 * K;

  f32x4 acc[4][2] = {};

  for (int kk = 0; kk < K; kk += 128) {
#pragma unroll
    for (int kh = 0; kh < 2; ++kh)
#pragma unroll
      for (int g = 0; g < 2; ++g) {
        int c = (w * 2 + g) * 64 + lane;
        int row = c >> 2, k8 = c & 3;
        const bf16* ga = Abase + (size_t)row * K + kk + kh * 64 + k8 * 8;
        async_cp16(ga, &As[kh * 2][(w * 2 + g) * 512]);
        async_cp16(ga + 32, &As[kh * 2 + 1][(w * 2 + g) * 512]);
      }
#pragma unroll
    for (int kh = 0; kh < 2; ++kh) {
      int c = w * 64 + lane;
      int row = c >> 2, k8 = c & 3;
      const bf16* gb = Wbase + (size_t)row * K + kk + kh * 64 + k8 * 8;
      async_cp16(gb, &Bs[kh * 2][w * 512]);
      async_cp16(gb + 32, &Bs[kh * 2 + 1][w * 512]);
    }
    __syncthreads();

#pragma unroll
    for (int ks = 0; ks < 4; ++ks) {
      bf16x8 af[4], bfr[2];
#pragma unroll
      for (int mi = 0; mi < 4; ++mi)
        af[mi] = *(const bf16x8*)&As[ks][(wr * 64 + mi * 16 + lm) * 32 + lq * 8];
#pragma unroll
      for (int ni = 0; ni < 2; ++ni)
        bfr[ni] = *(const bf16x8*)&Bs[ks][(wc * 32 + ni * 16 + lm) * 32 + lq * 8];
#pragma unroll
      for (int mi = 0; mi < 4; ++mi)
#pragma unroll
        for (int ni = 0; ni < 2; ++ni)
          acc[mi][ni] = __builtin_amdgcn_mfma_f32_16x16x32_bf16(
              af[mi], bfr[ni], acc[mi][ni], 0, 0, 0);
    }
    __syncthreads();
  }

  // C/D layout: col = lane&15, row = (lane>>4)*4 + reg (m89/m91-verified)
  if (z < 2) {
    const float scale = (z == 0) ? 0.125f : 1.0f;  // 1/sqrt(DH) folded into q
#pragma unroll
    for (int mi = 0; mi < 4; ++mi)
#pragma unroll
      for (int ni = 0; ni < 2; ++ni) {
        int gcol = bn * 64 + wc * 32 + ni * 16 + lm;
        int p = (gcol & 63) >> 1;
        bool even = (gcol & 1) == 0;
#pragma unroll
        for (int r = 0; r < 4; ++r) {
          int row = bm * 128 + wr * 64 + mi * 16 + lq * 4 + r;
          float v = acc[mi][ni][r];
          float mate = __shfl_xor(v, 1);   // partner col of the rope pair
          float cv = cosT[row * 32 + p];
          float sv = sinT[row * 32 + p];
          float res = even ? (v * cv - mate * sv) : (mate * sv + v * cv);
          C[(size_t)row * N + gcol] = (bf16)(res * scale);
        }
      }
  } else {
#pragma unroll
    for (int mi = 0; mi < 4; ++mi)
#pragma unroll
      for (int ni = 0; ni < 2; ++ni) {
        int gcol = bn * 64 + wc * 32 + ni * 16 + lm;      // d index
        int rowb = bm * 128 + wr * 64 + mi * 16 + lq * 4; // s index base
        bf16x4 pack;
#pragma unroll
        for (int r = 0; r < 4; ++r) pack[r] = (bf16)acc[mi][ni][r];
        *(bf16x4*)(Vt + (size_t)gcol * S_LEN + rowb) = pack;
      }
  }
}

// ---------------------------------------------------------------------------
// Output GEMM (R9 — measured best): out = ao @ Wo^T, 64x64 tile, BK=128,
// DMA staging, 2-barrier K-loop, fp32 direct store.
__global__ __launch_bounds__(256) void gemm_wo(
    const bf16* __restrict__ A, const bf16* __restrict__ W,
    float* __restrict__ C)
{
  constexpr int K = 1024, N = 1024;

  __shared__ bf16 As[4][64 * 32] __attribute__((aligned(16)));
  __shared__ bf16 Bs[4][64 * 32] __attribute__((aligned(16)));

  const int t = threadIdx.x;
  const int lane = t & 63;
  const int w = t >> 6;
  const int lm = lane & 15, lq = lane >> 4;
  const int bn = blockIdx.x, bm = blockIdx.y;

  const bf16* Abase = A + (size_t)bm * 64 * K;
  const bf16* Wbase = W + (size_t)bn * 64 * K;

  f32x4 acc[4] = {};

  for (int kk = 0; kk < K; kk += 128) {
#pragma unroll
    for (int kh = 0; kh < 2; ++kh) {
      int c = w * 64 + lane;
      int row = c >> 2, k8 = c & 3;
      const bf16* ga = Abase + (size_t)row * K + kk + kh * 64 + k8 * 8;
      async_cp16(ga, &As[kh * 2][w * 512]);
      async_cp16(ga + 32, &As[kh * 2 + 1][w * 512]);
      const bf16* gb = Wbase + (size_t)row * K + kk + kh * 64 + k8 * 8;
      async_cp16(gb, &Bs[kh * 2][w * 512]);
      async_cp16(gb + 32, &Bs[kh * 2 + 1][w * 512]);
    }
    __syncthreads();

#pragma unroll
    for (int ks = 0; ks < 4; ++ks) {
      bf16x8 af = *(const bf16x8*)&As[ks][(w * 16 + lm) * 32 + lq * 8];
      bf16x8 bfr[4];
#pragma unroll
      for (int ni = 0; ni < 4; ++ni)
        bfr[ni] = *(const bf16x8*)&Bs[ks][(ni * 16 + lm) * 32 + lq * 8];
#pragma unroll
      for (int ni = 0; ni < 4; ++ni)
        acc[ni] = __builtin_amdgcn_mfma_f32_16x16x32_bf16(
            af, bfr[ni], acc[ni], 0, 0, 0);
    }
    __syncthreads();
  }

#pragma unroll
  for (int ni = 0; ni < 4; ++ni) {
    int col = bn * 64 + ni * 16 + lm;
#pragma unroll
    for (int r = 0; r < 4; ++r) {
      int row = bm * 64 + w * 16 + lq * 4 + r;
      C[(size_t)row * N + col] = acc[ni][r];
    }
  }
}

// ---------------------------------------------------------------------------
// Flash attention (R9 core) + FUSED split-K combine: the last of the NPAR
// parity blocks per (qt,h) — determined by a device-scope ACQ_REL atomic
// ticket on a pre-zeroed counter — sums the 4 fp32 partials and writes the
// normalized bf16 ao rows. Removes the combine dispatch; combine work
// overlaps the attn tail.
__global__ __launch_bounds__(256) void attn_k(
    const bf16* __restrict__ Q, const bf16* __restrict__ Kmat,
    const bf16* __restrict__ Vt, const int* __restrict__ seg,
    const int* __restrict__ kbr,
    float* __restrict__ Opar, float* __restrict__ Lpar,
    int* __restrict__ cnt, bf16* __restrict__ AO)
{
  __shared__ bf16 Ks[64 * 72] __attribute__((aligned(16)));    // [key][dh]
  __shared__ bf16 Vs[64 * 72] __attribute__((aligned(16)));    // [dh][key]
  __shared__ bf16 Ps[4][16 * 72] __attribute__((aligned(16))); // per-wave P
  __shared__ int segk[64];
  __shared__ int lastFlag;

  const int h = blockIdx.y;
  const int qt = blockIdx.x & 31, par = blockIdx.x >> 5;
  const int q0 = qt * 64;
  const int t = threadIdx.x, lane = t & 63, w = t >> 6;
  const int lm = lane & 15, lq = lane >> 4;
  const int qrow = q0 + w * 16;

  const int kb0f = kbr[qt * 2], kb1f = kbr[qt * 2 + 1];  // inclusive

  bf16x8 qf[2];  // A-operand: m = lane&15, k = quad*8+j
#pragma unroll
  for (int ks = 0; ks < 2; ++ks)
    qf[ks] = *(const bf16x8*)(Q + (size_t)(qrow + lm) * D_DIM + h * DHEAD +
                              ks * 32 + lq * 8);

  int sq[4];
  float l_i[4];  // per-LANE partials (reduced once at the end)
#pragma unroll
  for (int r = 0; r < 4; ++r) {
    sq[r] = seg[qrow + lq * 4 + r];
    l_i[r] = 0.0f;
  }
  f32x4 o[4] = {};

  const int srow0 = t >> 3, sch = (t & 7) * 8;
  const int srow1 = (256 + t) >> 3;

  const int kbS = kb0f + par;
  f32x4 pk0, pk1, pv0, pv1;
  int psg;
  if (kbS <= kb1f) {
    const int k0 = kbS * 64;
    pk0 = *(const f32x4*)(Kmat + (size_t)(k0 + srow0) * D_DIM + h * DHEAD + sch);
    pk1 = *(const f32x4*)(Kmat + (size_t)(k0 + srow1) * D_DIM + h * DHEAD + sch);
    pv0 = *(const f32x4*)(Vt + (size_t)(h * DHEAD + srow0) * S_LEN + k0 + sch);
    pv1 = *(const f32x4*)(Vt + (size_t)(h * DHEAD + srow1) * S_LEN + k0 + sch);
    if (t < 64) psg = seg[k0 + t];
  }

  for (int kb = kbS; kb <= kb1f; kb += NPAR) {
    __syncthreads();
    *(f32x4*)&Ks[srow0 * 72 + sch] = pk0;
    *(f32x4*)&Ks[srow1 * 72 + sch] = pk1;
    *(f32x4*)&Vs[srow0 * 72 + sch] = pv0;
    *(f32x4*)&Vs[srow1 * 72 + sch] = pv1;
    if (t < 64) segk[t] = psg;
    __syncthreads();

    if (kb + NPAR <= kb1f) {  // prefetch next assigned tile (uniform branch)
      const int k0 = (kb + NPAR) * 64;
      pk0 = *(const f32x4*)(Kmat + (size_t)(k0 + srow0) * D_DIM + h * DHEAD + sch);
      pk1 = *(const f32x4*)(Kmat + (size_t)(k0 + srow1) * D_DIM + h * DHEAD + sch);
      pv0 = *(const f32x4*)(Vt + (size_t)(h * DHEAD + srow0) * S_LEN + k0 + sch);
      pv1 = *(const f32x4*)(Vt + (size_t)(h * DHEAD + srow1) * S_LEN + k0 + sch);
      if (t < 64) psg = seg[k0 + t];
    }

    // S = Q K^T (Q pre-scaled by 1/sqrt(DH) in the QKV epilogue)
    f32x4 sa[4] = {};
#pragma unroll
    for (int ks = 0; ks < 2; ++ks) {
      bf16x8 kf[4];
#pragma unroll
      for (int ni = 0; ni < 4; ++ni)
        kf[ni] = *(const bf16x8*)&Ks[(ni * 16 + lm) * 72 + ks * 32 + lq * 8];
#pragma unroll
      for (int ni = 0; ni < 4; ++ni)
        sa[ni] = __builtin_amdgcn_mfma_f32_16x16x32_bf16(qf[ks], kf[ni],
                                                         sa[ni], 0, 0, 0);
    }

    int sk[4];
#pragma unroll
    for (int ni = 0; ni < 4; ++ni) sk[ni] = segk[ni * 16 + lm];

#pragma unroll
    for (int r = 0; r < 4; ++r)
#pragma unroll
      for (int ni = 0; ni < 4; ++ni) {
        float p = (sq[r] == sk[ni]) ? __expf(sa[ni][r]) : 0.0f;
        l_i[r] += p;
        Ps[w][(lq * 4 + r) * 72 + ni * 16 + lm] = (bf16)p;
      }

    // O += P @ V
#pragma unroll
    for (int ks = 0; ks < 2; ++ks) {
      bf16x8 pf = *(const bf16x8*)&Ps[w][lm * 72 + ks * 32 + lq * 8];
      bf16x8 vf[4];
#pragma unroll
      for (int ni = 0; ni < 4; ++ni)
        vf[ni] = *(const bf16x8*)&Vs[(ni * 16 + lm) * 72 + ks * 32 + lq * 8];
#pragma unroll
      for (int ni = 0; ni < 4; ++ni)
        o[ni] = __builtin_amdgcn_mfma_f32_16x16x32_bf16(pf, vf[ni], o[ni],
                                                        0, 0, 0);
    }
  }

  // write this parity's unnormalized partials
  float* Ob = Opar + ((size_t)(par * NHEAD + h) * S_LEN) * DHEAD;
  float* Lb = Lpar + (size_t)(par * NHEAD + h) * S_LEN;
#pragma unroll
  for (int r = 0; r < 4; ++r) {
    float l = l_i[r];
    l += __shfl_xor(l, 1);
    l += __shfl_xor(l, 2);
    l += __shfl_xor(l, 4);
    l += __shfl_xor(l, 8);
    int row = qrow + lq * 4 + r;
    if (lm == 0) Lb[row] = l;
#pragma unroll
    for (int ni = 0; ni < 4; ++ni)
      Ob[(size_t)row * DHEAD + ni * 16 + lm] = o[ni][r];
  }

  // ---- last-arrival combine (threadfence-reduction pattern) ----
  __threadfence();          // make this block's partial writes device-visible
  __syncthreads();
  if (t == 0) {
    int old = __hip_atomic_fetch_add(&cnt[h * 32 + qt], 1,
                                     __ATOMIC_ACQ_REL,
                                     __HIP_MEMORY_SCOPE_AGENT);
    lastFlag = (old == NPAR - 1);
  }
  __syncthreads();
  if (lastFlag) {
    const size_t PO = (size_t)NHEAD * S_LEN * DHEAD;
    const size_t PL = (size_t)NHEAD * S_LEN;
    for (int i = t; i < 64 * 16; i += 256) {   // 64 rows x 16 f32x4 chunks
      int row = q0 + (i >> 4);
      int c4 = i & 15;
      const float* o0 = Opar + ((size_t)h * S_LEN + row) * DHEAD + c4 * 4;
      f32x4 s = {0.f, 0.f, 0.f, 0.f};
      float l = 0.f;
#pragma unroll
      for (int p = 0; p < NPAR; ++p) {
        s += *(const f32x4*)(o0 + p * PO);
        l += Lpar[p * PL + (size_t)h * S_LEN + row];
      }
      float inv = 1.0f / l;
      bf16x4 ov;
#pragma unroll
      for (int j = 0; j < 4; ++j) ov[j] = (bf16)(s[j] * inv);
      *(bf16x4*)(AO + (size_t)row * D_DIM + h * DHEAD + c4 * 4) = ov;
    }
  }
}

// ---------------------------------------------------------------------------
extern "C" void kernel_launch(void* const* d_in, const int* in_sizes, int n_in,
                              void* d_out, int out_size, void* d_ws,
                              size_t ws_size, hipStream_t stream)
{
  const float* x  = (const float*)d_in[0];
  const int*   sg = (const int*)d_in[1];
  const float* fc = (const float*)d_in[2];
  const float* fs = (const float*)d_in[3];
  const float* wq = (const float*)d_in[4];
  const float* wk = (const float*)d_in[5];
  const float* wv = (const float*)d_in[6];
  const float* wo = (const float*)d_in[7];
  float* out = (float*)d_out;

  const size_t MAT = (size_t)S_LEN * D_DIM;  // 2M elements
  const size_t WSZ = (size_t)D_DIM * D_DIM;  // 1M elements
  bf16* xb  = (bf16*)d_ws;         // cvt_k writes xb..wob contiguous
  bf16* wqb = xb + MAT;
  bf16* wkb = wqb + WSZ;
  bf16* wvb = wkb + WSZ;
  bf16* wob = wvb + WSZ;
  bf16* q0  = wob + WSZ;           // rope'd+scaled, by gemm_qkv z=0
  bf16* k0  = q0 + MAT;            // rope'd, by gemm_qkv z=1
  bf16* vt  = k0 + MAT;            // V^T [1024][2048], by gemm_qkv z=2
  bf16* ao  = vt + MAT;            // attention output (bf16), by attn_k
  float* opar = (float*)(ao + MAT);          // NPAR x 16 x 2048 x 64 fp32
  float* lpar = opar + (size_t)NPAR * MAT;   // NPAR x 16 x 2048 fp32
  int*   kbr  = (int*)(lpar + (size_t)NPAR * NHEAD * S_LEN);  // 32 x 2
  int*   cnt  = kbr + 64;                    // 512 arrival counters

  dim3 blk(256);
  cvt_k<<<dim3(3073), blk, 0, stream>>>(x, wq, wk, wv, wo, xb, sg, kbr, cnt);
  gemm_qkv<<<dim3(16, 16, 3), blk, 0, stream>>>(xb, wqb, wkb, wvb, fc, fs,
                                                q0, vt);
  attn_k<<<dim3(32 * NPAR, 16), blk, 0, stream>>>(q0, k0, vt, sg, kbr,
                                                  opar, lpar, cnt, ao);
  gemm_wo<<<dim3(16, 32), blk, 0, stream>>>(ao, wob, out);
}

// Round 13
// 150.109 us; speedup vs baseline: 3.1049x; 3.1049x over previous
//
#include <hip/hip_runtime.h>

typedef __bf16 bf16;
typedef __bf16 bf16x4 __attribute__((ext_vector_type(4)));
typedef __bf16 bf16x8 __attribute__((ext_vector_type(8)));
typedef float  f32x4  __attribute__((ext_vector_type(4)));

#define S_LEN 2048
#define D_DIM 1024
#define NHEAD 16
#define DHEAD 64
#define NPAR 4

// ---------------------------------------------------------------------------
// async global->LDS, 16B per lane (wave-uniform LDS base + lane*16, m104).
__device__ __forceinline__ void async_cp16(const bf16* g, bf16* l) {
  __builtin_amdgcn_global_load_lds(
      (__attribute__((address_space(1))) void*)(void*)g,
      (__attribute__((address_space(3))) void*)l,
      16, 0, 0);
}

// ---------------------------------------------------------------------------
// fp32 -> bf16 cvt of x + 4 weights (blocks [0,3072)); block 3072 computes
// per-Q-tile key-block ranges kbr[32][2] from sorted seg_ids.
__global__ __launch_bounds__(256) void cvt_k(
    const float* __restrict__ x,  const float* __restrict__ w0,
    const float* __restrict__ w1, const float* __restrict__ w2,
    const float* __restrict__ w3, bf16* __restrict__ dst,
    const int* __restrict__ seg, int* __restrict__ kbr)
{
  __shared__ int firstv[4];
  const int b = blockIdx.x;
  const int t = threadIdx.x;

  if (b < 3072) {
    int i = b * 256 + t;  // 0 .. 786431 (x8 elems)
    const float* src;
    int off;
    if (i < (1 << 18)) {            // x: 2^18 groups of 8
      src = x; off = i;
    } else {
      int j = i - (1 << 18);        // weights: 2^17 groups each
      int s = j >> 17;
      off = j & ((1 << 17) - 1);
      src = (s == 0) ? w0 : (s == 1) ? w1 : (s == 2) ? w2 : w3;
    }
    f32x4 a = *(const f32x4*)(src + (size_t)off * 8);
    f32x4 bb = *(const f32x4*)(src + (size_t)off * 8 + 4);
    bf16x8 o;
    o[0] = (bf16)a[0];  o[1] = (bf16)a[1];  o[2] = (bf16)a[2];  o[3] = (bf16)a[3];
    o[4] = (bf16)bb[0]; o[5] = (bf16)bb[1]; o[6] = (bf16)bb[2]; o[7] = (bf16)bb[3];
    *((bf16x8*)dst + i) = o;
  } else {
    if (t < 4) firstv[t] = S_LEN;
    __syncthreads();
    for (int i = t; i < S_LEN; i += 256) {
      int s = seg[i];
      if (i == 0 || seg[i - 1] != s) atomicMin(&firstv[s], i);
    }
    __syncthreads();
    if (t < 32) {
      int smin = seg[t * 64], smax = seg[t * 64 + 63];
      int lb = S_LEN, ub = S_LEN;
      for (int vv = smin; vv < 4; ++vv) lb = min(lb, firstv[vv]);
      for (int vv = smax + 1; vv < 4; ++vv) ub = min(ub, firstv[vv]);
      kbr[t * 2] = lb >> 6;
      kbr[t * 2 + 1] = (ub - 1) >> 6;  // inclusive
    }
  }
}

// ---------------------------------------------------------------------------
// QKV GEMM: 128x128 tile (ladder sweet spot: 64 MFMA : 32 ds_read per iter),
// BK=128 via four split 32-k LDS arrays (64KB LDS; grid 384 = 1.5/CU so the
// 2-blocks/CU LDS cap is non-binding). DMA staging, 2-barrier K-loop.
// Waves: 2x2 grid of 64x64 quadrants, 4x4 MFMAs each. Epilogue by z:
// z=0 rope*0.125 -> q0; z=1 rope -> k0; z=2 transposed store -> Vt.
__global__ __launch_bounds__(256) void gemm_qkv(
    const bf16* __restrict__ A,
    const bf16* __restrict__ B0, const bf16* __restrict__ B1,
    const bf16* __restrict__ B2,
    const float* __restrict__ cosT, const float* __restrict__ sinT,
    bf16* __restrict__ Cbase, bf16* __restrict__ Vt)
{
  constexpr int K = 1024, N = 1024;
  const int z = blockIdx.z;
  const bf16* W = (z == 0) ? B0 : (z == 1) ? B1 : B2;
  bf16* C = Cbase + (size_t)z * 2048 * 1024;

  __shared__ bf16 As[4][128 * 32] __attribute__((aligned(16)));  // 32KB
  __shared__ bf16 Bs[4][128 * 32] __attribute__((aligned(16)));  // 32KB

  const int t = threadIdx.x;
  const int lane = t & 63;
  const int w = t >> 6;
  const int lm = lane & 15, lq = lane >> 4;
  const int wr = w >> 1, wc = w & 1;
  const int bm = blockIdx.y, bn = blockIdx.x;

  const bf16* Abase = A + (size_t)bm * 128 * K;
  const bf16* Wbase = W + (size_t)bn * 128 * K;

  f32x4 acc[4][4] = {};

  for (int kk = 0; kk < K; kk += 128) {
    // A and B: 128 rows x 128 k each. Per 64-k half kh, per group g:
    // chunk c=(w*2+g)*64+lane in [0,512); row=c>>2, k8=c&3; two cp16 split
    // the 64-k half into the two 32-k arrays.
#pragma unroll
    for (int kh = 0; kh < 2; ++kh)
#pragma unroll
      for (int g = 0; g < 2; ++g) {
        int c = (w * 2 + g) * 64 + lane;
        int row = c >> 2, k8 = c & 3;
        const bf16* ga = Abase + (size_t)row * K + kk + kh * 64 + k8 * 8;
        async_cp16(ga, &As[kh * 2][(w * 2 + g) * 512]);
        async_cp16(ga + 32, &As[kh * 2 + 1][(w * 2 + g) * 512]);
        const bf16* gb = Wbase + (size_t)row * K + kk + kh * 64 + k8 * 8;
        async_cp16(gb, &Bs[kh * 2][(w * 2 + g) * 512]);
        async_cp16(gb + 32, &Bs[kh * 2 + 1][(w * 2 + g) * 512]);
      }
    __syncthreads();

#pragma unroll
    for (int ks = 0; ks < 4; ++ks) {   // k = kk + ks*32 + lq*8
      bf16x8 af[4], bfr[4];
#pragma unroll
      for (int mi = 0; mi < 4; ++mi)
        af[mi] = *(const bf16x8*)&As[ks][(wr * 64 + mi * 16 + lm) * 32 + lq * 8];
#pragma unroll
      for (int ni = 0; ni < 4; ++ni)
        bfr[ni] = *(const bf16x8*)&Bs[ks][(wc * 64 + ni * 16 + lm) * 32 + lq * 8];
#pragma unroll
      for (int mi = 0; mi < 4; ++mi)
#pragma unroll
        for (int ni = 0; ni < 4; ++ni)
          acc[mi][ni] = __builtin_amdgcn_mfma_f32_16x16x32_bf16(
              af[mi], bfr[ni], acc[mi][ni], 0, 0, 0);
    }
    __syncthreads();
  }

  // C/D layout: col = lane&15, row = (lane>>4)*4 + reg (m89/m91-verified)
  if (z < 2) {
    const float scale = (z == 0) ? 0.125f : 1.0f;  // 1/sqrt(DH) folded into q
#pragma unroll
    for (int mi = 0; mi < 4; ++mi)
#pragma unroll
      for (int ni = 0; ni < 4; ++ni) {
        int gcol = bn * 128 + wc * 64 + ni * 16 + lm;
        int p = (gcol & 63) >> 1;          // rope pair within 64-wide head
        bool even = (gcol & 1) == 0;
#pragma unroll
        for (int r = 0; r < 4; ++r) {
          int row = bm * 128 + wr * 64 + mi * 16 + lq * 4 + r;
          float v = acc[mi][ni][r];
          float mate = __shfl_xor(v, 1);   // partner col of the rope pair
          float cv = cosT[row * 32 + p];
          float sv = sinT[row * 32 + p];
          float res = even ? (v * cv - mate * sv) : (mate * sv + v * cv);
          C[(size_t)row * N + gcol] = (bf16)(res * scale);
        }
      }
  } else {
    // V: write transposed, 4 consecutive s-rows -> one 8B store
#pragma unroll
    for (int mi = 0; mi < 4; ++mi)
#pragma unroll
      for (int ni = 0; ni < 4; ++ni) {
        int gcol = bn * 128 + wc * 64 + ni * 16 + lm;     // d index
        int rowb = bm * 128 + wr * 64 + mi * 16 + lq * 4; // s index base
        bf16x4 pack;
#pragma unroll
        for (int r = 0; r < 4; ++r) pack[r] = (bf16)acc[mi][ni][r];
        *(bf16x4*)(Vt + (size_t)gcol * S_LEN + rowb) = pack;
      }
  }
}

// ---------------------------------------------------------------------------
// Output GEMM (R9 — measured best): out = ao @ Wo^T, 64x64 tile, BK=128,
// DMA staging, 2-barrier K-loop, fp32 direct store.
__global__ __launch_bounds__(256) void gemm_wo(
    const bf16* __restrict__ A, const bf16* __restrict__ W,
    float* __restrict__ C)
{
  constexpr int K = 1024, N = 1024;

  __shared__ bf16 As[4][64 * 32] __attribute__((aligned(16)));
  __shared__ bf16 Bs[4][64 * 32] __attribute__((aligned(16)));

  const int t = threadIdx.x;
  const int lane = t & 63;
  const int w = t >> 6;
  const int lm = lane & 15, lq = lane >> 4;
  const int bn = blockIdx.x, bm = blockIdx.y;

  const bf16* Abase = A + (size_t)bm * 64 * K;
  const bf16* Wbase = W + (size_t)bn * 64 * K;

  f32x4 acc[4] = {};

  for (int kk = 0; kk < K; kk += 128) {
#pragma unroll
    for (int kh = 0; kh < 2; ++kh) {
      int c = w * 64 + lane;
      int row = c >> 2, k8 = c & 3;
      const bf16* ga = Abase + (size_t)row * K + kk + kh * 64 + k8 * 8;
      async_cp16(ga, &As[kh * 2][w * 512]);
      async_cp16(ga + 32, &As[kh * 2 + 1][w * 512]);
      const bf16* gb = Wbase + (size_t)row * K + kk + kh * 64 + k8 * 8;
      async_cp16(gb, &Bs[kh * 2][w * 512]);
      async_cp16(gb + 32, &Bs[kh * 2 + 1][w * 512]);
    }
    __syncthreads();

#pragma unroll
    for (int ks = 0; ks < 4; ++ks) {
      bf16x8 af = *(const bf16x8*)&As[ks][(w * 16 + lm) * 32 + lq * 8];
      bf16x8 bfr[4];
#pragma unroll
      for (int ni = 0; ni < 4; ++ni)
        bfr[ni] = *(const bf16x8*)&Bs[ks][(ni * 16 + lm) * 32 + lq * 8];
#pragma unroll
      for (int ni = 0; ni < 4; ++ni)
        acc[ni] = __builtin_amdgcn_mfma_f32_16x16x32_bf16(
            af, bfr[ni], acc[ni], 0, 0, 0);
    }
    __syncthreads();
  }

#pragma unroll
  for (int ni = 0; ni < 4; ++ni) {
    int col = bn * 64 + ni * 16 + lm;
#pragma unroll
    for (int r = 0; r < 4; ++r) {
      int row = bm * 64 + w * 16 + lq * 4 + r;
      C[(size_t)row * N + col] = acc[ni][r];
    }
  }
}

// ---------------------------------------------------------------------------
// Flash attention (R9 — measured best): Q-tile 64, no-max softmax, split-K
// x4 (blockIdx.x = par*32 + qt). Unnormalized fp32 partials (O, l);
// combine_k reduces. Register-prefetch staging; no shuffles in the loop.
__global__ __launch_bounds__(256) void attn_k(
    const bf16* __restrict__ Q, const bf16* __restrict__ Kmat,
    const bf16* __restrict__ Vt, const int* __restrict__ seg,
    const int* __restrict__ kbr,
    float* __restrict__ Opar, float* __restrict__ Lpar)
{
  __shared__ bf16 Ks[64 * 72] __attribute__((aligned(16)));    // [key][dh]
  __shared__ bf16 Vs[64 * 72] __attribute__((aligned(16)));    // [dh][key]
  __shared__ bf16 Ps[4][16 * 72] __attribute__((aligned(16))); // per-wave P
  __shared__ int segk[64];

  const int h = blockIdx.y;
  const int qt = blockIdx.x & 31, par = blockIdx.x >> 5;
  const int q0 = qt * 64;
  const int t = threadIdx.x, lane = t & 63, w = t >> 6;
  const int lm = lane & 15, lq = lane >> 4;
  const int qrow = q0 + w * 16;

  const int kb0f = kbr[qt * 2], kb1f = kbr[qt * 2 + 1];  // inclusive

  bf16x8 qf[2];  // A-operand: m = lane&15, k = quad*8+j
#pragma unroll
  for (int ks = 0; ks < 2; ++ks)
    qf[ks] = *(const bf16x8*)(Q + (size_t)(qrow + lm) * D_DIM + h * DHEAD +
                              ks * 32 + lq * 8);

  int sq[4];
  float l_i[4];  // per-LANE partials (reduced once at the end)
#pragma unroll
  for (int r = 0; r < 4; ++r) {
    sq[r] = seg[qrow + lq * 4 + r];
    l_i[r] = 0.0f;
  }
  f32x4 o[4] = {};

  const int srow0 = t >> 3, sch = (t & 7) * 8;
  const int srow1 = (256 + t) >> 3;

  const int kbS = kb0f + par;
  f32x4 pk0, pk1, pv0, pv1;
  int psg;
  if (kbS <= kb1f) {
    const int k0 = kbS * 64;
    pk0 = *(const f32x4*)(Kmat + (size_t)(k0 + srow0) * D_DIM + h * DHEAD + sch);
    pk1 = *(const f32x4*)(Kmat + (size_t)(k0 + srow1) * D_DIM + h * DHEAD + sch);
    pv0 = *(const f32x4*)(Vt + (size_t)(h * DHEAD + srow0) * S_LEN + k0 + sch);
    pv1 = *(const f32x4*)(Vt + (size_t)(h * DHEAD + srow1) * S_LEN + k0 + sch);
    if (t < 64) psg = seg[k0 + t];
  }

  for (int kb = kbS; kb <= kb1f; kb += NPAR) {
    __syncthreads();
    *(f32x4*)&Ks[srow0 * 72 + sch] = pk0;
    *(f32x4*)&Ks[srow1 * 72 + sch] = pk1;
    *(f32x4*)&Vs[srow0 * 72 + sch] = pv0;
    *(f32x4*)&Vs[srow1 * 72 + sch] = pv1;
    if (t < 64) segk[t] = psg;
    __syncthreads();

    if (kb + NPAR <= kb1f) {  // prefetch next assigned tile (uniform branch)
      const int k0 = (kb + NPAR) * 64;
      pk0 = *(const f32x4*)(Kmat + (size_t)(k0 + srow0) * D_DIM + h * DHEAD + sch);
      pk1 = *(const f32x4*)(Kmat + (size_t)(k0 + srow1) * D_DIM + h * DHEAD + sch);
      pv0 = *(const f32x4*)(Vt + (size_t)(h * DHEAD + srow0) * S_LEN + k0 + sch);
      pv1 = *(const f32x4*)(Vt + (size_t)(h * DHEAD + srow1) * S_LEN + k0 + sch);
      if (t < 64) psg = seg[k0 + t];
    }

    // S = Q K^T (Q pre-scaled by 1/sqrt(DH) in the QKV epilogue)
    f32x4 sa[4] = {};
#pragma unroll
    for (int ks = 0; ks < 2; ++ks) {
      bf16x8 kf[4];
#pragma unroll
      for (int ni = 0; ni < 4; ++ni)
        kf[ni] = *(const bf16x8*)&Ks[(ni * 16 + lm) * 72 + ks * 32 + lq * 8];
#pragma unroll
      for (int ni = 0; ni < 4; ++ni)
        sa[ni] = __builtin_amdgcn_mfma_f32_16x16x32_bf16(qf[ks], kf[ni],
                                                         sa[ni], 0, 0, 0);
    }

    int sk[4];
#pragma unroll
    for (int ni = 0; ni < 4; ++ni) sk[ni] = segk[ni * 16 + lm];

#pragma unroll
    for (int r = 0; r < 4; ++r)
#pragma unroll
      for (int ni = 0; ni < 4; ++ni) {
        float p = (sq[r] == sk[ni]) ? __expf(sa[ni][r]) : 0.0f;
        l_i[r] += p;
        Ps[w][(lq * 4 + r) * 72 + ni * 16 + lm] = (bf16)p;
      }

    // O += P @ V
#pragma unroll
    for (int ks = 0; ks < 2; ++ks) {
      bf16x8 pf = *(const bf16x8*)&Ps[w][lm * 72 + ks * 32 + lq * 8];
      bf16x8 vf[4];
#pragma unroll
      for (int ni = 0; ni < 4; ++ni)
        vf[ni] = *(const bf16x8*)&Vs[(ni * 16 + lm) * 72 + ks * 32 + lq * 8];
#pragma unroll
      for (int ni = 0; ni < 4; ++ni)
        o[ni] = __builtin_amdgcn_mfma_f32_16x16x32_bf16(pf, vf[ni], o[ni],
                                                        0, 0, 0);
    }
  }

  float* Ob = Opar + ((size_t)(par * NHEAD + h) * S_LEN) * DHEAD;
  float* Lb = Lpar + (size_t)(par * NHEAD + h) * S_LEN;
#pragma unroll
  for (int r = 0; r < 4; ++r) {
    float l = l_i[r];
    l += __shfl_xor(l, 1);
    l += __shfl_xor(l, 2);
    l += __shfl_xor(l, 4);
    l += __shfl_xor(l, 8);
    int row = qrow + lq * 4 + r;
    if (lm == 0) Lb[row] = l;
#pragma unroll
    for (int ni = 0; ni < 4; ++ni)
      Ob[(size_t)row * DHEAD + ni * 16 + lm] = o[ni][r];
  }
}

// ---------------------------------------------------------------------------
// AO[row][h*64+c] = sum_par O / sum_par l, bf16. One thread = 4 cols.
__global__ __launch_bounds__(256) void combine_k(
    const float* __restrict__ Opar, const float* __restrict__ Lpar,
    bf16* __restrict__ AO)
{
  int idx = blockIdx.x * 256 + threadIdx.x;  // 0 .. 524287
  int c4 = idx & 15;
  int rh = idx >> 4;
  int row = rh & 2047;
  int h = rh >> 11;
  const size_t PO = (size_t)NHEAD * S_LEN * DHEAD;  // parity stride (floats)
  const size_t PL = (size_t)NHEAD * S_LEN;
  const float* o0 = Opar + ((size_t)h * S_LEN + row) * DHEAD + c4 * 4;
  f32x4 s = {0.f, 0.f, 0.f, 0.f};
  float l = 0.f;
#pragma unroll
  for (int p = 0; p < NPAR; ++p) {
    s += *(const f32x4*)(o0 + p * PO);
    l += Lpar[p * PL + (size_t)h * S_LEN + row];
  }
  float inv = 1.0f / l;
  bf16x4 ov;
#pragma unroll
  for (int j = 0; j < 4; ++j) ov[j] = (bf16)(s[j] * inv);
  *(bf16x4*)(AO + (size_t)row * D_DIM + h * DHEAD + c4 * 4) = ov;
}

// ---------------------------------------------------------------------------
extern "C" void kernel_launch(void* const* d_in, const int* in_sizes, int n_in,
                              void* d_out, int out_size, void* d_ws,
                              size_t ws_size, hipStream_t stream)
{
  const float* x  = (const float*)d_in[0];
  const int*   sg = (const int*)d_in[1];
  const float* fc = (const float*)d_in[2];
  const float* fs = (const float*)d_in[3];
  const float* wq = (const float*)d_in[4];
  const float* wk = (const float*)d_in[5];
  const float* wv = (const float*)d_in[6];
  const float* wo = (const float*)d_in[7];
  float* out = (float*)d_out;

  const size_t MAT = (size_t)S_LEN * D_DIM;  // 2M elements
  const size_t WSZ = (size_t)D_DIM * D_DIM;  // 1M elements
  bf16* xb  = (bf16*)d_ws;         // cvt_k writes xb..wob contiguous
  bf16* wqb = xb + MAT;
  bf16* wkb = wqb + WSZ;
  bf16* wvb = wkb + WSZ;
  bf16* wob = wvb + WSZ;
  bf16* q0  = wob + WSZ;           // rope'd+scaled, by gemm_qkv z=0
  bf16* k0  = q0 + MAT;            // rope'd, by gemm_qkv z=1
  bf16* vt  = k0 + MAT;            // V^T [1024][2048], by gemm_qkv z=2
  bf16* ao  = vt + MAT;            // attention output (bf16)
  float* opar = (float*)(ao + MAT);          // NPAR x 16 x 2048 x 64 fp32
  float* lpar = opar + (size_t)NPAR * MAT;   // NPAR x 16 x 2048 fp32
  int*   kbr  = (int*)(lpar + (size_t)NPAR * NHEAD * S_LEN);  // 32 x 2

  dim3 blk(256);
  cvt_k<<<dim3(3073), blk, 0, stream>>>(x, wq, wk, wv, wo, xb, sg, kbr);
  gemm_qkv<<<dim3(8, 16, 3), blk, 0, stream>>>(xb, wqb, wkb, wvb, fc, fs,
                                               q0, vt);
  attn_k<<<dim3(32 * NPAR, 16), blk, 0, stream>>>(q0, k0, vt, sg, kbr,
                                                  opar, lpar);
  combine_k<<<dim3(2048), blk, 0, stream>>>(opar, lpar, ao);
  gemm_wo<<<dim3(16, 32), blk, 0, stream>>>(ao, wob, out);
}

// Round 14
// 145.765 us; speedup vs baseline: 3.1974x; 1.0298x over previous
//
#include <hip/hip_runtime.h>

typedef __bf16 bf16;
typedef __bf16 bf16x4 __attribute__((ext_vector_type(4)));
typedef __bf16 bf16x8 __attribute__((ext_vector_type(8)));
typedef float  f32x4  __attribute__((ext_vector_type(4)));
typedef _Float16 f16;
typedef f16 f16x4 __attribute__((ext_vector_type(4)));

#define S_LEN 2048
#define D_DIM 1024
#define NHEAD 16
#define DHEAD 64
#define NPAR 4

// ---------------------------------------------------------------------------
// async global->LDS, 16B per lane (wave-uniform LDS base + lane*16, m104).
__device__ __forceinline__ void async_cp16(const bf16* g, bf16* l) {
  __builtin_amdgcn_global_load_lds(
      (__attribute__((address_space(1))) void*)(void*)g,
      (__attribute__((address_space(3))) void*)l,
      16, 0, 0);
}

// ---------------------------------------------------------------------------
// fp32 -> bf16 cvt of x + 4 weights (blocks [0,3072)); block 3072 computes
// per-Q-tile key-block ranges kbr[32][2] from sorted seg_ids.
__global__ __launch_bounds__(256) void cvt_k(
    const float* __restrict__ x,  const float* __restrict__ w0,
    const float* __restrict__ w1, const float* __restrict__ w2,
    const float* __restrict__ w3, bf16* __restrict__ dst,
    const int* __restrict__ seg, int* __restrict__ kbr)
{
  __shared__ int firstv[4];
  const int b = blockIdx.x;
  const int t = threadIdx.x;

  if (b < 3072) {
    int i = b * 256 + t;  // 0 .. 786431 (x8 elems)
    const float* src;
    int off;
    if (i < (1 << 18)) {            // x: 2^18 groups of 8
      src = x; off = i;
    } else {
      int j = i - (1 << 18);        // weights: 2^17 groups each
      int s = j >> 17;
      off = j & ((1 << 17) - 1);
      src = (s == 0) ? w0 : (s == 1) ? w1 : (s == 2) ? w2 : w3;
    }
    f32x4 a = *(const f32x4*)(src + (size_t)off * 8);
    f32x4 bb = *(const f32x4*)(src + (size_t)off * 8 + 4);
    bf16x8 o;
    o[0] = (bf16)a[0];  o[1] = (bf16)a[1];  o[2] = (bf16)a[2];  o[3] = (bf16)a[3];
    o[4] = (bf16)bb[0]; o[5] = (bf16)bb[1]; o[6] = (bf16)bb[2]; o[7] = (bf16)bb[3];
    *((bf16x8*)dst + i) = o;
  } else {
    if (t < 4) firstv[t] = S_LEN;
    __syncthreads();
    for (int i = t; i < S_LEN; i += 256) {
      int s = seg[i];
      if (i == 0 || seg[i - 1] != s) atomicMin(&firstv[s], i);
    }
    __syncthreads();
    if (t < 32) {
      int smin = seg[t * 64], smax = seg[t * 64 + 63];
      int lb = S_LEN, ub = S_LEN;
      for (int vv = smin; vv < 4; ++vv) lb = min(lb, firstv[vv]);
      for (int vv = smax + 1; vv < 4; ++vv) ub = min(ub, firstv[vv]);
      kbr[t * 2] = lb >> 6;
      kbr[t * 2 + 1] = (ub - 1) >> 6;  // inclusive
    }
  }
}

// ---------------------------------------------------------------------------
// QKV GEMM (R9 — measured best): 128x64 tile, BK=128 via four split 32-k
// LDS arrays (48KB, 3 blocks/CU), DMA staging, 2-barrier K-loop. Epilogue
// by z: z=0 rope*0.125 -> q0; z=1 rope -> k0; z=2 transposed store -> Vt.
__global__ __launch_bounds__(256) void gemm_qkv(
    const bf16* __restrict__ A,
    const bf16* __restrict__ B0, const bf16* __restrict__ B1,
    const bf16* __restrict__ B2,
    const float* __restrict__ cosT, const float* __restrict__ sinT,
    bf16* __restrict__ Cbase, bf16* __restrict__ Vt)
{
  constexpr int K = 1024, N = 1024;
  const int z = blockIdx.z;
  const bf16* W = (z == 0) ? B0 : (z == 1) ? B1 : B2;
  bf16* C = Cbase + (size_t)z * 2048 * 1024;

  __shared__ bf16 As[4][128 * 32] __attribute__((aligned(16)));  // 32KB
  __shared__ bf16 Bs[4][64 * 32] __attribute__((aligned(16)));   // 16KB

  const int t = threadIdx.x;
  const int lane = t & 63;
  const int w = t >> 6;
  const int lm = lane & 15, lq = lane >> 4;
  const int wr = w >> 1, wc = w & 1;
  const int bm = blockIdx.y, bn = blockIdx.x;

  const bf16* Abase = A + (size_t)bm * 128 * K;
  const bf16* Wbase = W + (size_t)bn * 64 * K;

  f32x4 acc[4][2] = {};

  for (int kk = 0; kk < K; kk += 128) {
#pragma unroll
    for (int kh = 0; kh < 2; ++kh)
#pragma unroll
      for (int g = 0; g < 2; ++g) {
        int c = (w * 2 + g) * 64 + lane;
        int row = c >> 2, k8 = c & 3;
        const bf16* ga = Abase + (size_t)row * K + kk + kh * 64 + k8 * 8;
        async_cp16(ga, &As[kh * 2][(w * 2 + g) * 512]);
        async_cp16(ga + 32, &As[kh * 2 + 1][(w * 2 + g) * 512]);
      }
#pragma unroll
    for (int kh = 0; kh < 2; ++kh) {
      int c = w * 64 + lane;
      int row = c >> 2, k8 = c & 3;
      const bf16* gb = Wbase + (size_t)row * K + kk + kh * 64 + k8 * 8;
      async_cp16(gb, &Bs[kh * 2][w * 512]);
      async_cp16(gb + 32, &Bs[kh * 2 + 1][w * 512]);
    }
    __syncthreads();

#pragma unroll
    for (int ks = 0; ks < 4; ++ks) {
      bf16x8 af[4], bfr[2];
#pragma unroll
      for (int mi = 0; mi < 4; ++mi)
        af[mi] = *(const bf16x8*)&As[ks][(wr * 64 + mi * 16 + lm) * 32 + lq * 8];
#pragma unroll
      for (int ni = 0; ni < 2; ++ni)
        bfr[ni] = *(const bf16x8*)&Bs[ks][(wc * 32 + ni * 16 + lm) * 32 + lq * 8];
#pragma unroll
      for (int mi = 0; mi < 4; ++mi)
#pragma unroll
        for (int ni = 0; ni < 2; ++ni)
          acc[mi][ni] = __builtin_amdgcn_mfma_f32_16x16x32_bf16(
              af[mi], bfr[ni], acc[mi][ni], 0, 0, 0);
    }
    __syncthreads();
  }

  // C/D layout: col = lane&15, row = (lane>>4)*4 + reg (m89/m91-verified)
  if (z < 2) {
    const float scale = (z == 0) ? 0.125f : 1.0f;  // 1/sqrt(DH) folded into q
#pragma unroll
    for (int mi = 0; mi < 4; ++mi)
#pragma unroll
      for (int ni = 0; ni < 2; ++ni) {
        int gcol = bn * 64 + wc * 32 + ni * 16 + lm;
        int p = (gcol & 63) >> 1;
        bool even = (gcol & 1) == 0;
#pragma unroll
        for (int r = 0; r < 4; ++r) {
          int row = bm * 128 + wr * 64 + mi * 16 + lq * 4 + r;
          float v = acc[mi][ni][r];
          float mate = __shfl_xor(v, 1);   // partner col of the rope pair
          float cv = cosT[row * 32 + p];
          float sv = sinT[row * 32 + p];
          float res = even ? (v * cv - mate * sv) : (mate * sv + v * cv);
          C[(size_t)row * N + gcol] = (bf16)(res * scale);
        }
      }
  } else {
#pragma unroll
    for (int mi = 0; mi < 4; ++mi)
#pragma unroll
      for (int ni = 0; ni < 2; ++ni) {
        int gcol = bn * 64 + wc * 32 + ni * 16 + lm;      // d index
        int rowb = bm * 128 + wr * 64 + mi * 16 + lq * 4; // s index base
        bf16x4 pack;
#pragma unroll
        for (int r = 0; r < 4; ++r) pack[r] = (bf16)acc[mi][ni][r];
        *(bf16x4*)(Vt + (size_t)gcol * S_LEN + rowb) = pack;
      }
  }
}

// ---------------------------------------------------------------------------
// Output GEMM (R9 — measured best): out = ao @ Wo^T, 64x64 tile, BK=128,
// DMA staging, 2-barrier K-loop, fp32 direct store.
__global__ __launch_bounds__(256) void gemm_wo(
    const bf16* __restrict__ A, const bf16* __restrict__ W,
    float* __restrict__ C)
{
  constexpr int K = 1024, N = 1024;

  __shared__ bf16 As[4][64 * 32] __attribute__((aligned(16)));
  __shared__ bf16 Bs[4][64 * 32] __attribute__((aligned(16)));

  const int t = threadIdx.x;
  const int lane = t & 63;
  const int w = t >> 6;
  const int lm = lane & 15, lq = lane >> 4;
  const int bn = blockIdx.x, bm = blockIdx.y;

  const bf16* Abase = A + (size_t)bm * 64 * K;
  const bf16* Wbase = W + (size_t)bn * 64 * K;

  f32x4 acc[4] = {};

  for (int kk = 0; kk < K; kk += 128) {
#pragma unroll
    for (int kh = 0; kh < 2; ++kh) {
      int c = w * 64 + lane;
      int row = c >> 2, k8 = c & 3;
      const bf16* ga = Abase + (size_t)row * K + kk + kh * 64 + k8 * 8;
      async_cp16(ga, &As[kh * 2][w * 512]);
      async_cp16(ga + 32, &As[kh * 2 + 1][w * 512]);
      const bf16* gb = Wbase + (size_t)row * K + kk + kh * 64 + k8 * 8;
      async_cp16(gb, &Bs[kh * 2][w * 512]);
      async_cp16(gb + 32, &Bs[kh * 2 + 1][w * 512]);
    }
    __syncthreads();

#pragma unroll
    for (int ks = 0; ks < 4; ++ks) {
      bf16x8 af = *(const bf16x8*)&As[ks][(w * 16 + lm) * 32 + lq * 8];
      bf16x8 bfr[4];
#pragma unroll
      for (int ni = 0; ni < 4; ++ni)
        bfr[ni] = *(const bf16x8*)&Bs[ks][(ni * 16 + lm) * 32 + lq * 8];
#pragma unroll
      for (int ni = 0; ni < 4; ++ni)
        acc[ni] = __builtin_amdgcn_mfma_f32_16x16x32_bf16(
            af, bfr[ni], acc[ni], 0, 0, 0);
    }
    __syncthreads();
  }

#pragma unroll
  for (int ni = 0; ni < 4; ++ni) {
    int col = bn * 64 + ni * 16 + lm;
#pragma unroll
    for (int r = 0; r < 4; ++r) {
      int row = bm * 64 + w * 16 + lq * 4 + r;
      C[(size_t)row * N + col] = acc[ni][r];
    }
  }
}

// ---------------------------------------------------------------------------
// Flash attention (R9 core): Q-tile 64, no-max softmax, split-K x4
// (blockIdx.x = par*32 + qt). Partials: O as f16 (halves Opar HBM traffic;
// |O|<~1e3 << f16 max, rel err 5e-4 << error budget), l as fp32.
__global__ __launch_bounds__(256) void attn_k(
    const bf16* __restrict__ Q, const bf16* __restrict__ Kmat,
    const bf16* __restrict__ Vt, const int* __restrict__ seg,
    const int* __restrict__ kbr,
    f16* __restrict__ Opar, float* __restrict__ Lpar)
{
  __shared__ bf16 Ks[64 * 72] __attribute__((aligned(16)));    // [key][dh]
  __shared__ bf16 Vs[64 * 72] __attribute__((aligned(16)));    // [dh][key]
  __shared__ bf16 Ps[4][16 * 72] __attribute__((aligned(16))); // per-wave P
  __shared__ int segk[64];

  const int h = blockIdx.y;
  const int qt = blockIdx.x & 31, par = blockIdx.x >> 5;
  const int q0 = qt * 64;
  const int t = threadIdx.x, lane = t & 63, w = t >> 6;
  const int lm = lane & 15, lq = lane >> 4;
  const int qrow = q0 + w * 16;

  const int kb0f = kbr[qt * 2], kb1f = kbr[qt * 2 + 1];  // inclusive

  bf16x8 qf[2];  // A-operand: m = lane&15, k = quad*8+j
#pragma unroll
  for (int ks = 0; ks < 2; ++ks)
    qf[ks] = *(const bf16x8*)(Q + (size_t)(qrow + lm) * D_DIM + h * DHEAD +
                              ks * 32 + lq * 8);

  int sq[4];
  float l_i[4];  // per-LANE partials (reduced once at the end)
#pragma unroll
  for (int r = 0; r < 4; ++r) {
    sq[r] = seg[qrow + lq * 4 + r];
    l_i[r] = 0.0f;
  }
  f32x4 o[4] = {};

  const int srow0 = t >> 3, sch = (t & 7) * 8;
  const int srow1 = (256 + t) >> 3;

  const int kbS = kb0f + par;
  f32x4 pk0, pk1, pv0, pv1;
  int psg;
  if (kbS <= kb1f) {
    const int k0 = kbS * 64;
    pk0 = *(const f32x4*)(Kmat + (size_t)(k0 + srow0) * D_DIM + h * DHEAD + sch);
    pk1 = *(const f32x4*)(Kmat + (size_t)(k0 + srow1) * D_DIM + h * DHEAD + sch);
    pv0 = *(const f32x4*)(Vt + (size_t)(h * DHEAD + srow0) * S_LEN + k0 + sch);
    pv1 = *(const f32x4*)(Vt + (size_t)(h * DHEAD + srow1) * S_LEN + k0 + sch);
    if (t < 64) psg = seg[k0 + t];
  }

  for (int kb = kbS; kb <= kb1f; kb += NPAR) {
    __syncthreads();
    *(f32x4*)&Ks[srow0 * 72 + sch] = pk0;
    *(f32x4*)&Ks[srow1 * 72 + sch] = pk1;
    *(f32x4*)&Vs[srow0 * 72 + sch] = pv0;
    *(f32x4*)&Vs[srow1 * 72 + sch] = pv1;
    if (t < 64) segk[t] = psg;
    __syncthreads();

    if (kb + NPAR <= kb1f) {  // prefetch next assigned tile (uniform branch)
      const int k0 = (kb + NPAR) * 64;
      pk0 = *(const f32x4*)(Kmat + (size_t)(k0 + srow0) * D_DIM + h * DHEAD + sch);
      pk1 = *(const f32x4*)(Kmat + (size_t)(k0 + srow1) * D_DIM + h * DHEAD + sch);
      pv0 = *(const f32x4*)(Vt + (size_t)(h * DHEAD + srow0) * S_LEN + k0 + sch);
      pv1 = *(const f32x4*)(Vt + (size_t)(h * DHEAD + srow1) * S_LEN + k0 + sch);
      if (t < 64) psg = seg[k0 + t];
    }

    // S = Q K^T (Q pre-scaled by 1/sqrt(DH) in the QKV epilogue)
    f32x4 sa[4] = {};
#pragma unroll
    for (int ks = 0; ks < 2; ++ks) {
      bf16x8 kf[4];
#pragma unroll
      for (int ni = 0; ni < 4; ++ni)
        kf[ni] = *(const bf16x8*)&Ks[(ni * 16 + lm) * 72 + ks * 32 + lq * 8];
#pragma unroll
      for (int ni = 0; ni < 4; ++ni)
        sa[ni] = __builtin_amdgcn_mfma_f32_16x16x32_bf16(qf[ks], kf[ni],
                                                         sa[ni], 0, 0, 0);
    }

    int sk[4];
#pragma unroll
    for (int ni = 0; ni < 4; ++ni) sk[ni] = segk[ni * 16 + lm];

#pragma unroll
    for (int r = 0; r < 4; ++r)
#pragma unroll
      for (int ni = 0; ni < 4; ++ni) {
        float p = (sq[r] == sk[ni]) ? __expf(sa[ni][r]) : 0.0f;
        l_i[r] += p;
        Ps[w][(lq * 4 + r) * 72 + ni * 16 + lm] = (bf16)p;
      }

    // O += P @ V
#pragma unroll
    for (int ks = 0; ks < 2; ++ks) {
      bf16x8 pf = *(const bf16x8*)&Ps[w][lm * 72 + ks * 32 + lq * 8];
      bf16x8 vf[4];
#pragma unroll
      for (int ni = 0; ni < 4; ++ni)
        vf[ni] = *(const bf16x8*)&Vs[(ni * 16 + lm) * 72 + ks * 32 + lq * 8];
#pragma unroll
      for (int ni = 0; ni < 4; ++ni)
        o[ni] = __builtin_amdgcn_mfma_f32_16x16x32_bf16(pf, vf[ni], o[ni],
                                                        0, 0, 0);
    }
  }

  f16* Ob = Opar + ((size_t)(par * NHEAD + h) * S_LEN) * DHEAD;
  float* Lb = Lpar + (size_t)(par * NHEAD + h) * S_LEN;
#pragma unroll
  for (int r = 0; r < 4; ++r) {
    float l = l_i[r];
    l += __shfl_xor(l, 1);
    l += __shfl_xor(l, 2);
    l += __shfl_xor(l, 4);
    l += __shfl_xor(l, 8);
    int row = qrow + lq * 4 + r;
    if (lm == 0) Lb[row] = l;
#pragma unroll
    for (int ni = 0; ni < 4; ++ni)
      Ob[(size_t)row * DHEAD + ni * 16 + lm] = (f16)o[ni][r];
  }
}

// ---------------------------------------------------------------------------
// AO[row][h*64+c] = sum_par O / sum_par l, bf16. One thread = 4 cols.
__global__ __launch_bounds__(256) void combine_k(
    const f16* __restrict__ Opar, const float* __restrict__ Lpar,
    bf16* __restrict__ AO)
{
  int idx = blockIdx.x * 256 + threadIdx.x;  // 0 .. 524287
  int c4 = idx & 15;
  int rh = idx >> 4;
  int row = rh & 2047;
  int h = rh >> 11;
  const size_t PO = (size_t)NHEAD * S_LEN * DHEAD;  // parity stride (elems)
  const size_t PL = (size_t)NHEAD * S_LEN;
  const f16* o0 = Opar + ((size_t)h * S_LEN + row) * DHEAD + c4 * 4;
  f32x4 s = {0.f, 0.f, 0.f, 0.f};
  float l = 0.f;
#pragma unroll
  for (int p = 0; p < NPAR; ++p) {
    f16x4 v = *(const f16x4*)(o0 + p * PO);
#pragma unroll
    for (int j = 0; j < 4; ++j) s[j] += (float)v[j];
    l += Lpar[p * PL + (size_t)h * S_LEN + row];
  }
  float inv = 1.0f / l;
  bf16x4 ov;
#pragma unroll
  for (int j = 0; j < 4; ++j) ov[j] = (bf16)(s[j] * inv);
  *(bf16x4*)(AO + (size_t)row * D_DIM + h * DHEAD + c4 * 4) = ov;
}

// ---------------------------------------------------------------------------
extern "C" void kernel_launch(void* const* d_in, const int* in_sizes, int n_in,
                              void* d_out, int out_size, void* d_ws,
                              size_t ws_size, hipStream_t stream)
{
  const float* x  = (const float*)d_in[0];
  const int*   sg = (const int*)d_in[1];
  const float* fc = (const float*)d_in[2];
  const float* fs = (const float*)d_in[3];
  const float* wq = (const float*)d_in[4];
  const float* wk = (const float*)d_in[5];
  const float* wv = (const float*)d_in[6];
  const float* wo = (const float*)d_in[7];
  float* out = (float*)d_out;

  const size_t MAT = (size_t)S_LEN * D_DIM;  // 2M elements
  const size_t WSZ = (size_t)D_DIM * D_DIM;  // 1M elements
  bf16* xb  = (bf16*)d_ws;         // cvt_k writes xb..wob contiguous
  bf16* wqb = xb + MAT;
  bf16* wkb = wqb + WSZ;
  bf16* wvb = wkb + WSZ;
  bf16* wob = wvb + WSZ;
  bf16* q0  = wob + WSZ;           // rope'd+scaled, by gemm_qkv z=0
  bf16* k0  = q0 + MAT;            // rope'd, by gemm_qkv z=1
  bf16* vt  = k0 + MAT;            // V^T [1024][2048], by gemm_qkv z=2
  bf16* ao  = vt + MAT;            // attention output (bf16)
  f16*  opar = (f16*)(ao + MAT);             // NPAR x 16 x 2048 x 64 f16
  float* lpar = (float*)(opar + (size_t)NPAR * MAT);  // NPAR x 16 x 2048 f32
  int*   kbr  = (int*)(lpar + (size_t)NPAR * NHEAD * S_LEN);  // 32 x 2

  dim3 blk(256);
  cvt_k<<<dim3(3073), blk, 0, stream>>>(x, wq, wk, wv, wo, xb, sg, kbr);
  gemm_qkv<<<dim3(16, 16, 3), blk, 0, stream>>>(xb, wqb, wkb, wvb, fc, fs,
                                                q0, vt);
  attn_k<<<dim3(32 * NPAR, 16), blk, 0, stream>>>(q0, k0, vt, sg, kbr,
                                                  opar, lpar);
  combine_k<<<dim3(2048), blk, 0, stream>>>(opar, lpar, ao);
  gemm_wo<<<dim3(16, 32), blk, 0, stream>>>(ao, wob, out);
}